// Round 6
// baseline (190.523 us; speedup 1.0000x reference)
//
#include <hip/hip_runtime.h>

// DigitCaps dynamic routing — single fused kernel, one 512-thread block per
// batch element, NO cross-block communication.
// Round-5 lesson: cross-block sync costs ~33us/sync in __threadfence()
//   (buffer_wbl2 L2-writeback walks), regardless of barrier topology -> any
//   c-split/hw-split design is fence-bound. Stay sync-free.
// Round-3 lesson: __launch_bounds__(512,2) => 2 blocks/CU => 4 waves/SIMD
//   => 128-VGPR cap => ~170-float live set spills (102MB scratch writes).
//   Fix: __launch_bounds__(512,1) => 1 block/CU, 2 waves/SIMD, 256-VGPR cap.
// vs round-0 (49us): same algorithm, but 9 hw/thread instead of 18 and
// 2 waves/SIMD instead of 1 -> half the serial work, double latency hiding.
// Thread map: c = tid>>4 (0..31), slot = tid&15 (0..15), 9 hw per thread.

#define BB 128
#define CC 32
#define HWN 144   // 12*12
#define QQ 8      // IN_CAPS
#define OO 10     // OUT_CH
#define PP 16     // OUT_CAPS

__device__ __forceinline__ float squash16(float s) {
    // tid = o*16 + p : reduce s^2 over the 16 p-lanes (masks 1..8)
    float sn = s * s;
#pragma unroll
    for (int m = 1; m <= 8; m <<= 1) sn += __shfl_xor(sn, m);
    return s * (sqrtf(sn) / (1.f + sn));
}

__global__ __launch_bounds__(512, 1)
void digitcaps_routing(const float* __restrict__ x, const float* __restrict__ Wm,
                       float* __restrict__ out) {
    const int b    = blockIdx.x;
    const int tid  = threadIdx.x;
    const int c    = tid >> 4;   // 0..31
    const int slot = tid & 15;   // 0..15

    __shared__ float usum_s[CC * QQ];        // 1 KB
    __shared__ float Wv_s[CC * OO * QQ];     // 10 KB (running logit-weight acc)
    __shared__ float t_s[CC * OO * QQ];      // 10 KB
    __shared__ float v_s[OO * PP];           // 640 B

    const float* xc = x + ((size_t)b * CC + c) * (HWN * QQ);

    // ---- A: usum[c][q] = sum_hw x[b,c,hw,q] ----
    float us[QQ];
#pragma unroll
    for (int q = 0; q < QQ; ++q) us[q] = 0.f;
#pragma unroll
    for (int i = 0; i < 9; ++i) {            // 144 = 16 slots * 9
        const int hw = slot + (i << 4);
        const float4* p4 = (const float4*)(xc + hw * QQ);
        float4 a = p4[0], d = p4[1];
        us[0] += a.x; us[1] += a.y; us[2] += a.z; us[3] += a.w;
        us[4] += d.x; us[5] += d.y; us[6] += d.z; us[7] += d.w;
    }
#pragma unroll
    for (int m = 1; m <= 8; m <<= 1) {       // reduce over 16 slot lanes
#pragma unroll
        for (int q = 0; q < QQ; ++q) us[q] += __shfl_xor(us[q], m);
    }
    if (slot == 0) {
#pragma unroll
        for (int q = 0; q < QQ; ++q) usum_s[c * QQ + q] = us[q];
    }
    __syncthreads();

    // ---- B: v1 = squash(0.1 * Wm . usum)  (iter-1 c_ij is uniform 0.1) ----
    if (tid < OO * PP) {
        const int o = tid >> 4, p = tid & 15;
        float s = 0.f;
        for (int cc = 0; cc < CC; ++cc) {
            const float4* w4 = (const float4*)(Wm + (((cc * OO + o) * PP + p) * QQ));
            float4 w0 = w4[0], w1 = w4[1];
            const float* u0 = &usum_s[cc * QQ];
            s += w0.x * u0[0] + w0.y * u0[1] + w0.z * u0[2] + w0.w * u0[3]
               + w1.x * u0[4] + w1.y * u0[5] + w1.z * u0[6] + w1.w * u0[7];
        }
        s *= 0.1f;
        v_s[tid] = squash16(s);
    }
    __syncthreads();

    // ---- Wv_s = Wm . v1  (logit accumulator; b_ij additivity) ----
    if (tid < CC * OO) {
        const int cc = tid / OO, o = tid - cc * OO;
        float acc[QQ];
#pragma unroll
        for (int q = 0; q < QQ; ++q) acc[q] = 0.f;
        const float* wp = Wm + ((cc * OO + o) * PP) * QQ;
#pragma unroll
        for (int p = 0; p < PP; ++p) {
            const float vv = v_s[o * PP + p];
            const float4* w4 = (const float4*)(wp + p * QQ);
            float4 w0 = w4[0], w1 = w4[1];
            acc[0] += vv * w0.x; acc[1] += vv * w0.y; acc[2] += vv * w0.z; acc[3] += vv * w0.w;
            acc[4] += vv * w1.x; acc[5] += vv * w1.y; acc[6] += vv * w1.z; acc[7] += vv * w1.w;
        }
        float* dst = Wv_s + (cc * OO + o) * QQ;
#pragma unroll
        for (int q = 0; q < QQ; ++q) dst[q] = acc[q];
    }
    __syncthreads();

    // ---- Routing iterations 2 and 3 ----
    for (int iter = 0; iter < 2; ++iter) {
        // logit weights for this thread's c
        float wv[OO][QQ];
#pragma unroll
        for (int o = 0; o < OO; ++o)
#pragma unroll
            for (int q = 0; q < QQ; ++q) wv[o][q] = Wv_s[(c * OO + o) * QQ + q];

        float tl[OO][QQ];
#pragma unroll
        for (int o = 0; o < OO; ++o)
#pragma unroll
            for (int q = 0; q < QQ; ++q) tl[o][q] = 0.f;

#pragma unroll
        for (int i = 0; i < 9; ++i) {        // 9 hw per thread
            const int hw = slot + (i << 4);
            const float4* p4 = (const float4*)(xc + hw * QQ);
            float4 a = p4[0], d = p4[1];
            float u[QQ] = {a.x, a.y, a.z, a.w, d.x, d.y, d.z, d.w};
            float lg[OO];
            float mx = -1e30f;
#pragma unroll
            for (int o = 0; o < OO; ++o) {
                float t = 0.f;
#pragma unroll
                for (int q = 0; q < QQ; ++q) t += u[q] * wv[o][q];
                lg[o] = t;
                mx = fmaxf(mx, t);
            }
            float ssum = 0.f;
#pragma unroll
            for (int o = 0; o < OO; ++o) { lg[o] = __expf(lg[o] - mx); ssum += lg[o]; }
            const float inv = 1.f / ssum;
#pragma unroll
            for (int o = 0; o < OO; ++o) {
                const float cij = lg[o] * inv;
#pragma unroll
                for (int q = 0; q < QQ; ++q) tl[o][q] += cij * u[q];
            }
        }
        // reduce t over the 16 slot lanes
#pragma unroll
        for (int m = 1; m <= 8; m <<= 1) {
#pragma unroll
            for (int o = 0; o < OO; ++o)
#pragma unroll
                for (int q = 0; q < QQ; ++q) tl[o][q] += __shfl_xor(tl[o][q], m);
        }
        if (slot == 0) {
#pragma unroll
            for (int o = 0; o < OO; ++o)
#pragma unroll
                for (int q = 0; q < QQ; ++q) t_s[(c * OO + o) * QQ + q] = tl[o][q];
        }
        __syncthreads();

        // s[o,p] = sum_{c,q} Wm[c,o,p,q]*t[c,o,q] ; v = squash(s)
        if (tid < OO * PP) {
            const int o = tid >> 4, p = tid & 15;
            float s = 0.f;
            for (int cc = 0; cc < CC; ++cc) {
                const float4* w4 = (const float4*)(Wm + (((cc * OO + o) * PP + p) * QQ));
                float4 w0 = w4[0], w1 = w4[1];
                const float4* t4 = (const float4*)(t_s + (cc * OO + o) * QQ);
                float4 t0 = t4[0], t1 = t4[1];
                s += w0.x * t0.x + w0.y * t0.y + w0.z * t0.z + w0.w * t0.w
                   + w1.x * t1.x + w1.y * t1.y + w1.z * t1.z + w1.w * t1.w;
            }
            const float v = squash16(s);
            if (iter == 1) out[(size_t)b * (OO * PP) + tid] = v;
            else           v_s[tid] = v;
        }
        if (iter == 0) {
            __syncthreads();
            // Wv_s += Wm . v2
            if (tid < CC * OO) {
                const int cc = tid / OO, o = tid - cc * OO;
                float acc[QQ];
#pragma unroll
                for (int q = 0; q < QQ; ++q) acc[q] = 0.f;
                const float* wp = Wm + ((cc * OO + o) * PP) * QQ;
#pragma unroll
                for (int p = 0; p < PP; ++p) {
                    const float vv = v_s[o * PP + p];
                    const float4* w4 = (const float4*)(wp + p * QQ);
                    float4 w0 = w4[0], w1 = w4[1];
                    acc[0] += vv * w0.x; acc[1] += vv * w0.y; acc[2] += vv * w0.z; acc[3] += vv * w0.w;
                    acc[4] += vv * w1.x; acc[5] += vv * w1.y; acc[6] += vv * w1.z; acc[7] += vv * w1.w;
                }
                float* dst = Wv_s + (cc * OO + o) * QQ;
#pragma unroll
                for (int q = 0; q < QQ; ++q) dst[q] += acc[q];
            }
            __syncthreads();
        }
    }
}

extern "C" void kernel_launch(void* const* d_in, const int* in_sizes, int n_in,
                              void* d_out, int out_size, void* d_ws, size_t ws_size,
                              hipStream_t stream) {
    const float* x  = (const float*)d_in[0];   // [128,32,12,12,8]
    const float* Wm = (const float*)d_in[1];   // [1,1,32,10,16,8]
    float* out      = (float*)d_out;           // [128,10,16]
    digitcaps_routing<<<BB, 512, 0, stream>>>(x, Wm, out);
}

// Round 7
// 104.997 us; speedup vs baseline: 1.8146x; 1.8146x over previous
//
#include <hip/hip_runtime.h>

// DigitCaps dynamic routing — single fused kernel, one 512-thread block per
// batch element, NO cross-block communication.
// Round-5 lesson: cross-block sync costs ~30us/sync in agent-scope L2
//   writeback/invalidate (8 non-coherent XCD L2s) -> stay sync-free.
// Round-3/6 lesson: 512-thread blocks get a hard 128-VGPR budget regardless
//   of __launch_bounds__ 2nd arg; the old heavy loop's 160-float live set
//   (wv[10][8]+tl[10][8]) spills ~100MB of scratch.
// Fix this round: split the o-dimension across lane pairs. Softmax couples
//   the 10 output channels only through (max, sum) -> one shfl_xor(.,1)
//   exchange. Each thread holds wv[5][8]+tl[5][8] = 80 floats -> fits 128.
// Heavy thread map: c = tid>>4 (32), slot = (tid>>1)&7 (8), oh = tid&1 (2);
//   18 hw per thread, 5 o's per thread. 8 waves/block = 2 waves/SIMD.

#define BB 128
#define CC 32
#define HWN 144   // 12*12
#define QQ 8      // IN_CAPS
#define OO 10     // OUT_CH
#define PP 16     // OUT_CAPS
#define OH 5      // o's per lane-half

__device__ __forceinline__ float squash16(float s) {
    // tid = o*16 + p : reduce s^2 over the 16 p-lanes (masks 1..8)
    float sn = s * s;
#pragma unroll
    for (int m = 1; m <= 8; m <<= 1) sn += __shfl_xor(sn, m);
    return s * (sqrtf(sn) / (1.f + sn));
}

__global__ __launch_bounds__(512, 1)
void digitcaps_routing(const float* __restrict__ x, const float* __restrict__ Wm,
                       float* __restrict__ out) {
    const int b   = blockIdx.x;
    const int tid = threadIdx.x;

    __shared__ float usum_s[CC * QQ];        // 1 KB
    __shared__ float Wv_s[CC * OO * QQ];     // 10 KB (running logit-weight acc)
    __shared__ float t_s[CC * OO * QQ];      // 10 KB
    __shared__ float v_s[OO * PP];           // 640 B

    // ---- A: usum[c][q] = sum_hw x[b,c,hw,q] ----  (c=tid>>4, slot=tid&15)
    {
        const int c = tid >> 4, slot = tid & 15;
        const float* xc = x + ((size_t)b * CC + c) * (HWN * QQ);
        float us[QQ];
#pragma unroll
        for (int q = 0; q < QQ; ++q) us[q] = 0.f;
#pragma unroll
        for (int i = 0; i < 9; ++i) {        // 144 = 16 slots * 9
            const int hw = slot + (i << 4);
            const float4* p4 = (const float4*)(xc + hw * QQ);
            float4 a = p4[0], d = p4[1];
            us[0] += a.x; us[1] += a.y; us[2] += a.z; us[3] += a.w;
            us[4] += d.x; us[5] += d.y; us[6] += d.z; us[7] += d.w;
        }
#pragma unroll
        for (int m = 1; m <= 8; m <<= 1) {   // reduce over 16 slot lanes
#pragma unroll
            for (int q = 0; q < QQ; ++q) us[q] += __shfl_xor(us[q], m);
        }
        if (slot == 0) {
#pragma unroll
            for (int q = 0; q < QQ; ++q) usum_s[c * QQ + q] = us[q];
        }
    }
    __syncthreads();

    // ---- B: v1 = squash(0.1 * Wm . usum) ----
    if (tid < OO * PP) {
        const int o = tid >> 4, p = tid & 15;
        float s = 0.f;
        for (int cc = 0; cc < CC; ++cc) {
            const float4* w4 = (const float4*)(Wm + (((cc * OO + o) * PP + p) * QQ));
            float4 w0 = w4[0], w1 = w4[1];
            const float* u0 = &usum_s[cc * QQ];
            s += w0.x * u0[0] + w0.y * u0[1] + w0.z * u0[2] + w0.w * u0[3]
               + w1.x * u0[4] + w1.y * u0[5] + w1.z * u0[6] + w1.w * u0[7];
        }
        s *= 0.1f;
        v_s[tid] = squash16(s);
    }
    __syncthreads();

    // ---- Wv_s = Wm . v1 ----  (tid < 320: one (c,o) each)
    if (tid < CC * OO) {
        const int cc = tid / OO, o = tid - cc * OO;
        float acc[QQ];
#pragma unroll
        for (int q = 0; q < QQ; ++q) acc[q] = 0.f;
        const float* wp = Wm + ((cc * OO + o) * PP) * QQ;
#pragma unroll
        for (int p = 0; p < PP; ++p) {
            const float vv = v_s[o * PP + p];
            const float4* w4 = (const float4*)(wp + p * QQ);
            float4 w0 = w4[0], w1 = w4[1];
            acc[0] += vv * w0.x; acc[1] += vv * w0.y; acc[2] += vv * w0.z; acc[3] += vv * w0.w;
            acc[4] += vv * w1.x; acc[5] += vv * w1.y; acc[6] += vv * w1.z; acc[7] += vv * w1.w;
        }
        float* dst = Wv_s + (cc * OO + o) * QQ;
#pragma unroll
        for (int q = 0; q < QQ; ++q) dst[q] = acc[q];
    }
    __syncthreads();

    // heavy-phase thread map
    const int hc    = tid >> 4;          // 0..31
    const int hslot = (tid >> 1) & 7;    // 0..7
    const int oh    = tid & 1;           // 0..1
    const int obase = oh * OH;
    const float* xhc = x + ((size_t)b * CC + hc) * (HWN * QQ);

    // ---- Routing iterations 2 and 3 ----
    for (int iter = 0; iter < 2; ++iter) {
        // this thread's 5 logit-weight rows
        float wv[OH][QQ];
#pragma unroll
        for (int j = 0; j < OH; ++j)
#pragma unroll
            for (int q = 0; q < QQ; ++q)
                wv[j][q] = Wv_s[(hc * OO + obase + j) * QQ + q];

        float tl[OH][QQ];
#pragma unroll
        for (int j = 0; j < OH; ++j)
#pragma unroll
            for (int q = 0; q < QQ; ++q) tl[j][q] = 0.f;

#pragma unroll 3
        for (int i = 0; i < 18; ++i) {   // 144 = 8 slots * 18
            const int hw = hslot + (i << 3);
            const float4* p4 = (const float4*)(xhc + hw * QQ);
            float4 a = p4[0], d = p4[1];
            float u[QQ] = {a.x, a.y, a.z, a.w, d.x, d.y, d.z, d.w};
            float lg[OH];
#pragma unroll
            for (int j = 0; j < OH; ++j) {
                float t = 0.f;
#pragma unroll
                for (int q = 0; q < QQ; ++q) t += u[q] * wv[j][q];
                lg[j] = t;
            }
            // global max over 10 o's: local 5-max + partner exchange
            float pm = fmaxf(fmaxf(fmaxf(lg[0], lg[1]), fmaxf(lg[2], lg[3])), lg[4]);
            pm = fmaxf(pm, __shfl_xor(pm, 1));
            float psum = 0.f;
#pragma unroll
            for (int j = 0; j < OH; ++j) { lg[j] = __expf(lg[j] - pm); psum += lg[j]; }
            psum += __shfl_xor(psum, 1);
            const float inv = 1.f / psum;
#pragma unroll
            for (int j = 0; j < OH; ++j) {
                const float cij = lg[j] * inv;
#pragma unroll
                for (int q = 0; q < QQ; ++q) tl[j][q] += cij * u[q];
            }
        }
        // reduce t over the 8 slot lanes (masks 2,4,8; oh stays separate)
#pragma unroll
        for (int m = 2; m <= 8; m <<= 1) {
#pragma unroll
            for (int j = 0; j < OH; ++j)
#pragma unroll
                for (int q = 0; q < QQ; ++q) tl[j][q] += __shfl_xor(tl[j][q], m);
        }
        if (hslot == 0) {                // both oh halves write their 5 o's
#pragma unroll
            for (int j = 0; j < OH; ++j)
#pragma unroll
                for (int q = 0; q < QQ; ++q)
                    t_s[(hc * OO + obase + j) * QQ + q] = tl[j][q];
        }
        __syncthreads();

        // s[o,p] = sum_{c,q} Wm[c,o,p,q]*t[c,o,q] ; v = squash(s)
        if (tid < OO * PP) {
            const int o = tid >> 4, p = tid & 15;
            float s = 0.f;
            for (int cc = 0; cc < CC; ++cc) {
                const float4* w4 = (const float4*)(Wm + (((cc * OO + o) * PP + p) * QQ));
                float4 w0 = w4[0], w1 = w4[1];
                const float4* t4 = (const float4*)(t_s + (cc * OO + o) * QQ);
                float4 t0 = t4[0], t1 = t4[1];
                s += w0.x * t0.x + w0.y * t0.y + w0.z * t0.z + w0.w * t0.w
                   + w1.x * t1.x + w1.y * t1.y + w1.z * t1.z + w1.w * t1.w;
            }
            const float v = squash16(s);
            if (iter == 1) out[(size_t)b * (OO * PP) + tid] = v;
            else           v_s[tid] = v;
        }
        if (iter == 0) {
            __syncthreads();
            // Wv_s += Wm . v2
            if (tid < CC * OO) {
                const int cc = tid / OO, o = tid - cc * OO;
                float acc[QQ];
#pragma unroll
                for (int q = 0; q < QQ; ++q) acc[q] = 0.f;
                const float* wp = Wm + ((cc * OO + o) * PP) * QQ;
#pragma unroll
                for (int p = 0; p < PP; ++p) {
                    const float vv = v_s[o * PP + p];
                    const float4* w4 = (const float4*)(wp + p * QQ);
                    float4 w0 = w4[0], w1 = w4[1];
                    acc[0] += vv * w0.x; acc[1] += vv * w0.y; acc[2] += vv * w0.z; acc[3] += vv * w0.w;
                    acc[4] += vv * w1.x; acc[5] += vv * w1.y; acc[6] += vv * w1.z; acc[7] += vv * w1.w;
                }
                float* dst = Wv_s + (cc * OO + o) * QQ;
#pragma unroll
                for (int q = 0; q < QQ; ++q) dst[q] += acc[q];
            }
            __syncthreads();
        }
    }
}

extern "C" void kernel_launch(void* const* d_in, const int* in_sizes, int n_in,
                              void* d_out, int out_size, void* d_ws, size_t ws_size,
                              hipStream_t stream) {
    const float* x  = (const float*)d_in[0];   // [128,32,12,12,8]
    const float* Wm = (const float*)d_in[1];   // [1,1,32,10,16,8]
    float* out      = (float*)d_out;           // [128,10,16]
    digitcaps_routing<<<BB, 512, 0, stream>>>(x, Wm, out);
}

// Round 8
// 101.870 us; speedup vs baseline: 1.8703x; 1.0307x over previous
//
#include <hip/hip_runtime.h>

// DigitCaps dynamic routing — single fused kernel, one 512-thread block per
// batch element, NO cross-block communication.
// Round-5 lesson: cross-block sync costs ~30us/sync (L2 wb/inv walks).
// Round-3/6 lesson: 512-thread blocks have a hard 128-VGPR budget; o-split
//   across lane pairs (round 7) fits it: VGPR=124, zero spill.
// Round-7 lesson: dur identical to round 0 (49.5us) despite 2x occupancy ->
//   bottleneck is the SHARED serial s-compute phases: 32-iter cc loops with
//   unpipelined dependent Wm loads (~500cy exposed latency x32 x3 phases),
//   run by 160/512 threads. This round: split each s-compute into two
//   16-cc halves (320 threads) + full unroll so loads pipeline.
// Heavy map: c = tid>>4 (32), slot=(tid>>1)&7 (8), oh=tid&1 (2), 18 hw,
//   5 o's per thread; softmax couples o-halves via one shfl_xor(.,1) pair.

#define BB 128
#define CC 32
#define HWN 144   // 12*12
#define QQ 8      // IN_CAPS
#define OO 10     // OUT_CH
#define PP 16     // OUT_CAPS
#define OH 5      // o's per lane-half

__device__ __forceinline__ float squash16(float s) {
    // tid = o*16 + p : reduce s^2 over the 16 p-lanes (masks 1..8)
    float sn = s * s;
#pragma unroll
    for (int m = 1; m <= 8; m <<= 1) sn += __shfl_xor(sn, m);
    return s * (sqrtf(sn) / (1.f + sn));
}

__global__ __launch_bounds__(512, 1)
void digitcaps_routing(const float* __restrict__ x, const float* __restrict__ Wm,
                       float* __restrict__ out) {
    const int b   = blockIdx.x;
    const int tid = threadIdx.x;

    __shared__ float usum_s[CC * QQ];        // 1 KB
    __shared__ float Wv_s[CC * OO * QQ];     // 10 KB (running logit-weight acc)
    __shared__ float t_s[CC * OO * QQ];      // 10 KB
    __shared__ float v_s[OO * PP];           // 640 B
    __shared__ float ps2_s[2 * OO * PP];     // 1.25 KB (cc-half partials)

    // ---- A: usum[c][q] = sum_hw x[b,c,hw,q] ----  (c=tid>>4, slot=tid&15)
    {
        const int c = tid >> 4, slot = tid & 15;
        const float* xc = x + ((size_t)b * CC + c) * (HWN * QQ);
        float us[QQ];
#pragma unroll
        for (int q = 0; q < QQ; ++q) us[q] = 0.f;
#pragma unroll
        for (int i = 0; i < 9; ++i) {        // 144 = 16 slots * 9
            const int hw = slot + (i << 4);
            const float4* p4 = (const float4*)(xc + hw * QQ);
            float4 a = p4[0], d = p4[1];
            us[0] += a.x; us[1] += a.y; us[2] += a.z; us[3] += a.w;
            us[4] += d.x; us[5] += d.y; us[6] += d.z; us[7] += d.w;
        }
#pragma unroll
        for (int m = 1; m <= 8; m <<= 1) {   // reduce over 16 slot lanes
#pragma unroll
            for (int q = 0; q < QQ; ++q) us[q] += __shfl_xor(us[q], m);
        }
        if (slot == 0) {
#pragma unroll
            for (int q = 0; q < QQ; ++q) usum_s[c * QQ + q] = us[q];
        }
    }
    __syncthreads();

    // ---- B: v1 = squash(0.1 * Wm . usum), split over 2 cc-halves ----
    if (tid < 2 * OO * PP) {
        const int h   = tid >= OO * PP;          // cc half
        const int idx = h ? tid - OO * PP : tid; // 0..159
        const int o = idx >> 4, p = idx & 15;
        const int c0 = h * 16;
        float s = 0.f;
#pragma unroll
        for (int k = 0; k < 16; ++k) {
            const int cc = c0 + k;
            const float4* w4 = (const float4*)(Wm + (((cc * OO + o) * PP + p) * QQ));
            float4 w0 = w4[0], w1 = w4[1];
            const float* u0 = &usum_s[cc * QQ];
            s += w0.x * u0[0] + w0.y * u0[1] + w0.z * u0[2] + w0.w * u0[3]
               + w1.x * u0[4] + w1.y * u0[5] + w1.z * u0[6] + w1.w * u0[7];
        }
        ps2_s[tid] = s;
    }
    __syncthreads();
    if (tid < OO * PP) {
        const float s = 0.1f * (ps2_s[tid] + ps2_s[OO * PP + tid]);
        v_s[tid] = squash16(s);
    }
    __syncthreads();

    // ---- Wv_s = Wm . v1 ----  (tid < 320: one (c,o) each)
    if (tid < CC * OO) {
        const int cc = tid / OO, o = tid - cc * OO;
        float acc[QQ];
#pragma unroll
        for (int q = 0; q < QQ; ++q) acc[q] = 0.f;
        const float* wp = Wm + ((cc * OO + o) * PP) * QQ;
#pragma unroll
        for (int p = 0; p < PP; ++p) {
            const float vv = v_s[o * PP + p];
            const float4* w4 = (const float4*)(wp + p * QQ);
            float4 w0 = w4[0], w1 = w4[1];
            acc[0] += vv * w0.x; acc[1] += vv * w0.y; acc[2] += vv * w0.z; acc[3] += vv * w0.w;
            acc[4] += vv * w1.x; acc[5] += vv * w1.y; acc[6] += vv * w1.z; acc[7] += vv * w1.w;
        }
        float* dst = Wv_s + (cc * OO + o) * QQ;
#pragma unroll
        for (int q = 0; q < QQ; ++q) dst[q] = acc[q];
    }
    __syncthreads();

    // heavy-phase thread map
    const int hc    = tid >> 4;          // 0..31
    const int hslot = (tid >> 1) & 7;    // 0..7
    const int oh    = tid & 1;           // 0..1
    const int obase = oh * OH;
    const float* xhc = x + ((size_t)b * CC + hc) * (HWN * QQ);

    // ---- Routing iterations 2 and 3 ----
    for (int iter = 0; iter < 2; ++iter) {
        // this thread's 5 logit-weight rows
        float wv[OH][QQ];
#pragma unroll
        for (int j = 0; j < OH; ++j)
#pragma unroll
            for (int q = 0; q < QQ; ++q)
                wv[j][q] = Wv_s[(hc * OO + obase + j) * QQ + q];

        float tl[OH][QQ];
#pragma unroll
        for (int j = 0; j < OH; ++j)
#pragma unroll
            for (int q = 0; q < QQ; ++q) tl[j][q] = 0.f;

#pragma unroll 3
        for (int i = 0; i < 18; ++i) {   // 144 = 8 slots * 18
            const int hw = hslot + (i << 3);
            const float4* p4 = (const float4*)(xhc + hw * QQ);
            float4 a = p4[0], d = p4[1];
            float u[QQ] = {a.x, a.y, a.z, a.w, d.x, d.y, d.z, d.w};
            float lg[OH];
#pragma unroll
            for (int j = 0; j < OH; ++j) {
                float t = 0.f;
#pragma unroll
                for (int q = 0; q < QQ; ++q) t += u[q] * wv[j][q];
                lg[j] = t;
            }
            // global max over 10 o's: local 5-max + partner exchange
            float pm = fmaxf(fmaxf(fmaxf(lg[0], lg[1]), fmaxf(lg[2], lg[3])), lg[4]);
            pm = fmaxf(pm, __shfl_xor(pm, 1));
            float psum = 0.f;
#pragma unroll
            for (int j = 0; j < OH; ++j) { lg[j] = __expf(lg[j] - pm); psum += lg[j]; }
            psum += __shfl_xor(psum, 1);
            const float inv = 1.f / psum;
#pragma unroll
            for (int j = 0; j < OH; ++j) {
                const float cij = lg[j] * inv;
#pragma unroll
                for (int q = 0; q < QQ; ++q) tl[j][q] += cij * u[q];
            }
        }
        // reduce t over the 8 slot lanes (masks 2,4,8; oh stays separate)
#pragma unroll
        for (int m = 2; m <= 8; m <<= 1) {
#pragma unroll
            for (int j = 0; j < OH; ++j)
#pragma unroll
                for (int q = 0; q < QQ; ++q) tl[j][q] += __shfl_xor(tl[j][q], m);
        }
        if (hslot == 0) {                // both oh halves write their 5 o's
#pragma unroll
            for (int j = 0; j < OH; ++j)
#pragma unroll
                for (int q = 0; q < QQ; ++q)
                    t_s[(hc * OO + obase + j) * QQ + q] = tl[j][q];
        }
        __syncthreads();

        // s[o,p] = sum_{c,q} Wm[c,o,p,q]*t[c,o,q], split over 2 cc-halves
        if (tid < 2 * OO * PP) {
            const int h   = tid >= OO * PP;
            const int idx = h ? tid - OO * PP : tid;
            const int o = idx >> 4, p = idx & 15;
            const int c0 = h * 16;
            float s = 0.f;
#pragma unroll
            for (int k = 0; k < 16; ++k) {
                const int cc = c0 + k;
                const float4* w4 = (const float4*)(Wm + (((cc * OO + o) * PP + p) * QQ));
                float4 w0 = w4[0], w1 = w4[1];
                const float4* t4 = (const float4*)(t_s + (cc * OO + o) * QQ);
                float4 t0 = t4[0], t1 = t4[1];
                s += w0.x * t0.x + w0.y * t0.y + w0.z * t0.z + w0.w * t0.w
                   + w1.x * t1.x + w1.y * t1.y + w1.z * t1.z + w1.w * t1.w;
            }
            ps2_s[tid] = s;
        }
        __syncthreads();
        if (tid < OO * PP) {
            const float s = ps2_s[tid] + ps2_s[OO * PP + tid];
            const float v = squash16(s);
            if (iter == 1) out[(size_t)b * (OO * PP) + tid] = v;
            else           v_s[tid] = v;
        }
        if (iter == 0) {
            __syncthreads();
            // Wv_s += Wm . v2
            if (tid < CC * OO) {
                const int cc = tid / OO, o = tid - cc * OO;
                float acc[QQ];
#pragma unroll
                for (int q = 0; q < QQ; ++q) acc[q] = 0.f;
                const float* wp = Wm + ((cc * OO + o) * PP) * QQ;
#pragma unroll
                for (int p = 0; p < PP; ++p) {
                    const float vv = v_s[o * PP + p];
                    const float4* w4 = (const float4*)(wp + p * QQ);
                    float4 w0 = w4[0], w1 = w4[1];
                    acc[0] += vv * w0.x; acc[1] += vv * w0.y; acc[2] += vv * w0.z; acc[3] += vv * w0.w;
                    acc[4] += vv * w1.x; acc[5] += vv * w1.y; acc[6] += vv * w1.z; acc[7] += vv * w1.w;
                }
                float* dst = Wv_s + (cc * OO + o) * QQ;
#pragma unroll
                for (int q = 0; q < QQ; ++q) dst[q] += acc[q];
            }
            __syncthreads();
        }
    }
}

extern "C" void kernel_launch(void* const* d_in, const int* in_sizes, int n_in,
                              void* d_out, int out_size, void* d_ws, size_t ws_size,
                              hipStream_t stream) {
    const float* x  = (const float*)d_in[0];   // [128,32,12,12,8]
    const float* Wm = (const float*)d_in[1];   // [1,1,32,10,16,8]
    float* out      = (float*)d_out;           // [128,10,16]
    digitcaps_routing<<<BB, 512, 0, stream>>>(x, Wm, out);
}

// Round 9
// 99.534 us; speedup vs baseline: 1.9141x; 1.0235x over previous
//
#include <hip/hip_runtime.h>

// DigitCaps dynamic routing — 2 blocks per batch (hw-split), fence-free
// cross-block exchange via coherent (agent-scope atomic) accesses only.
// Round-5 lesson: the ~30us/sync cost was __threadfence's L2 wb/inv walks,
//   not atomic contention -> move DATA through relaxed agent-scope atomics
//   (serviced at the coherent point, cross-XCD safe) and drop all fences.
//   Ordering: __syncthreads drains vmcnt(0) before s_barrier, so data
//   stores complete before the ticket add; readers load after the barrier.
// Round-3/6/7 lesson: 512-thread blocks have a hard 128-VGPR budget; the
//   o-split heavy map (wv[5][8]+tl[5][8], shfl_xor(.,1) softmax coupling)
//   fits it: VGPR=112, zero spill (round 8).
// Rounds 0/7/8 lesson: intra-block restructuring is invariant at ~45-50us;
//   128 blocks is the structural limit -> this round uses 256 blocks.
//
// Grid (2,128) x 512 thr = 256 blocks = 1/CU, 8 waves each. Block (bh,b)
// owns hw in [bh*72, bh*72+72), all 32 c. Only three 160-float s-partial
// exchanges cross blocks (s is linear in t; softmax is per-(hw,c) local).
// Tickets are monotone (6 per batch per launch) -> graph-replay safe.

#define BB 128
#define CC 32
#define HWN 144   // 12*12
#define HWH 72    // per-block hw half
#define QQ 8      // IN_CAPS
#define OO 10     // OUT_CH
#define PP 16     // OUT_CAPS
#define OH 5      // o's per lane-half

__device__ float    g_sx[3 * BB * 2 * OO * PP];  // [phase][b][bh][160]
__device__ unsigned g_cnt[BB * 32];              // per-batch tickets, 128B stride

__device__ __forceinline__ float squash16(float s) {
    // tid = o*16 + p : reduce s^2 over the 16 p-lanes (masks 1..8)
    float sn = s * s;
#pragma unroll
    for (int m = 1; m <= 8; m <<= 1) sn += __shfl_xor(sn, m);
    return s * (sqrtf(sn) / (1.f + sn));
}

__global__ __launch_bounds__(512, 1)
void digitcaps_routing(const float* __restrict__ x, const float* __restrict__ Wm,
                       float* __restrict__ out) {
    const int bh  = blockIdx.x;   // 0..1 hw half
    const int b   = blockIdx.y;   // 0..127
    const int tid = threadIdx.x;

    __shared__ float usum_s[CC * QQ];        // 1 KB   (partial over this half)
    __shared__ float Wv_s[CC * OO * QQ];     // 10 KB  (running logit-weight acc)
    __shared__ float t_s[CC * OO * QQ];      // 10 KB  (partial over this half)
    __shared__ float v_s[OO * PP];           // 640 B
    __shared__ float ps2_s[2 * OO * PP];     // 1.25 KB (cc-half partials)

    // ---- A: usum[c][q] = sum_{hw in half} x[b,c,hw,q] ----
    {
        const int c = tid >> 4, slot = tid & 15;
        const float* xc = x + (((size_t)b * CC + c) * HWN + bh * HWH) * QQ;
        float us[QQ];
#pragma unroll
        for (int q = 0; q < QQ; ++q) us[q] = 0.f;
#pragma unroll
        for (int i = 0; i < 5; ++i) {        // 72 = 16 slots * 4.5
            const int hwl = slot + (i << 4);
            if (hwl < HWH) {
                const float4* p4 = (const float4*)(xc + hwl * QQ);
                float4 a = p4[0], d = p4[1];
                us[0] += a.x; us[1] += a.y; us[2] += a.z; us[3] += a.w;
                us[4] += d.x; us[5] += d.y; us[6] += d.z; us[7] += d.w;
            }
        }
#pragma unroll
        for (int m = 1; m <= 8; m <<= 1) {
#pragma unroll
            for (int q = 0; q < QQ; ++q) us[q] += __shfl_xor(us[q], m);
        }
        if (slot == 0) {
#pragma unroll
            for (int q = 0; q < QQ; ++q) usum_s[c * QQ + q] = us[q];
        }
    }
    __syncthreads();

    // heavy-phase thread map (fixed for the whole kernel)
    const int hc    = tid >> 4;          // 0..31
    const int hslot = (tid >> 1) & 7;    // 0..7
    const int oh    = tid & 1;           // 0..1
    const int obase = oh * OH;
    const float* xhc = x + (((size_t)b * CC + hc) * HWN + bh * HWH) * QQ;

    // ---- 3 phases: ph=0 -> v1 seed; ph=1,2 -> routing iters ----
    for (int ph = 0; ph < 3; ++ph) {
        // local partial s[o,p], split over 2 cc-halves (320 threads)
        if (tid < 2 * OO * PP) {
            const int h   = tid >= OO * PP;
            const int idx = h ? tid - OO * PP : tid;
            const int o = idx >> 4, p = idx & 15;
            const int c0 = h * 16;
            float s = 0.f;
#pragma unroll
            for (int k = 0; k < 16; ++k) {
                const int cc = c0 + k;
                const float4* w4 = (const float4*)(Wm + (((cc * OO + o) * PP + p) * QQ));
                float4 w0 = w4[0], w1 = w4[1];
                const float* src = (ph == 0) ? &usum_s[cc * QQ]
                                             : &t_s[(cc * OO + o) * QQ];
                s += w0.x * src[0] + w0.y * src[1] + w0.z * src[2] + w0.w * src[3]
                   + w1.x * src[4] + w1.y * src[5] + w1.z * src[6] + w1.w * src[7];
            }
            ps2_s[tid] = s;
        }
        __syncthreads();

        // ---- exchange 160-float s-partial with partner block ----
        const int spin = (ph < 2) ? 1 : (bh == 0);
        float sown = 0.f;
        if (tid < OO * PP) {
            sown = ps2_s[tid] + ps2_s[OO * PP + tid];
            __hip_atomic_store(&g_sx[(((size_t)ph * BB + b) * 2 + bh) * (OO * PP) + tid],
                               sown, __ATOMIC_RELAXED, __HIP_MEMORY_SCOPE_AGENT);
        }
        __syncthreads();   // drains vmcnt(0): stores are at the coherent point
        if (tid == 0) {
            unsigned t = __hip_atomic_fetch_add(&g_cnt[b * 32], 1u,
                             __ATOMIC_RELAXED, __HIP_MEMORY_SCOPE_AGENT);
            if (spin) {
                const unsigned target = (t / 2u + 1u) * 2u;
                while (__hip_atomic_load(&g_cnt[b * 32], __ATOMIC_RELAXED,
                                         __HIP_MEMORY_SCOPE_AGENT) < target)
                    __builtin_amdgcn_s_sleep(1);
            }
        }
        __syncthreads();
        if (!spin) break;  // bh1 at ph==2: posted, done (no output to write)

        // combine partials -> v (or final output)
        if (tid < OO * PP) {
            float soth = __hip_atomic_load(
                &g_sx[(((size_t)ph * BB + b) * 2 + (1 - bh)) * (OO * PP) + tid],
                __ATOMIC_RELAXED, __HIP_MEMORY_SCOPE_AGENT);
            float s = sown + soth;
            if (ph == 0) s *= 0.1f;          // iter-1 uniform c_ij
            const float v = squash16(s);
            if (ph == 2) { out[(size_t)b * (OO * PP) + tid] = v; }
            else         { v_s[tid] = v; }
        }
        if (ph == 2) break;
        __syncthreads();

        // ---- Wv (set on ph0, accumulate on ph1): Wv += Wm . v ----
        if (tid < CC * OO) {
            const int cc = tid / OO, o = tid - cc * OO;
            float acc[QQ];
#pragma unroll
            for (int q = 0; q < QQ; ++q) acc[q] = 0.f;
            const float* wp = Wm + ((cc * OO + o) * PP) * QQ;
#pragma unroll
            for (int p = 0; p < PP; ++p) {
                const float vv = v_s[o * PP + p];
                const float4* w4 = (const float4*)(wp + p * QQ);
                float4 w0 = w4[0], w1 = w4[1];
                acc[0] += vv * w0.x; acc[1] += vv * w0.y; acc[2] += vv * w0.z; acc[3] += vv * w0.w;
                acc[4] += vv * w1.x; acc[5] += vv * w1.y; acc[6] += vv * w1.z; acc[7] += vv * w1.w;
            }
            float* dst = Wv_s + (cc * OO + o) * QQ;
            if (ph == 0) {
#pragma unroll
                for (int q = 0; q < QQ; ++q) dst[q] = acc[q];
            } else {
#pragma unroll
                for (int q = 0; q < QQ; ++q) dst[q] += acc[q];
            }
        }
        __syncthreads();

        // ---- heavy: logits = u.Wv, softmax over o, t = sum_hw c_ij*u ----
        float wv[OH][QQ];
#pragma unroll
        for (int j = 0; j < OH; ++j)
#pragma unroll
            for (int q = 0; q < QQ; ++q)
                wv[j][q] = Wv_s[(hc * OO + obase + j) * QQ + q];

        float tl[OH][QQ];
#pragma unroll
        for (int j = 0; j < OH; ++j)
#pragma unroll
            for (int q = 0; q < QQ; ++q) tl[j][q] = 0.f;

#pragma unroll 3
        for (int i = 0; i < 9; ++i) {        // 72 = 8 slots * 9
            const int hwl = hslot + (i << 3);
            const float4* p4 = (const float4*)(xhc + hwl * QQ);
            float4 a = p4[0], d = p4[1];
            float u[QQ] = {a.x, a.y, a.z, a.w, d.x, d.y, d.z, d.w};
            float lg[OH];
#pragma unroll
            for (int j = 0; j < OH; ++j) {
                float t = 0.f;
#pragma unroll
                for (int q = 0; q < QQ; ++q) t += u[q] * wv[j][q];
                lg[j] = t;
            }
            float pm = fmaxf(fmaxf(fmaxf(lg[0], lg[1]), fmaxf(lg[2], lg[3])), lg[4]);
            pm = fmaxf(pm, __shfl_xor(pm, 1));
            float psum = 0.f;
#pragma unroll
            for (int j = 0; j < OH; ++j) { lg[j] = __expf(lg[j] - pm); psum += lg[j]; }
            psum += __shfl_xor(psum, 1);
            const float inv = 1.f / psum;
#pragma unroll
            for (int j = 0; j < OH; ++j) {
                const float cij = lg[j] * inv;
#pragma unroll
                for (int q = 0; q < QQ; ++q) tl[j][q] += cij * u[q];
            }
        }
        // reduce t over the 8 slot lanes (masks 2,4,8; oh stays separate)
#pragma unroll
        for (int m = 2; m <= 8; m <<= 1) {
#pragma unroll
            for (int j = 0; j < OH; ++j)
#pragma unroll
                for (int q = 0; q < QQ; ++q) tl[j][q] += __shfl_xor(tl[j][q], m);
        }
        if (hslot == 0) {
#pragma unroll
            for (int j = 0; j < OH; ++j)
#pragma unroll
                for (int q = 0; q < QQ; ++q)
                    t_s[(hc * OO + obase + j) * QQ + q] = tl[j][q];
        }
        __syncthreads();
    }
}

extern "C" void kernel_launch(void* const* d_in, const int* in_sizes, int n_in,
                              void* d_out, int out_size, void* d_ws, size_t ws_size,
                              hipStream_t stream) {
    const float* x  = (const float*)d_in[0];   // [128,32,12,12,8]
    const float* Wm = (const float*)d_in[1];   // [1,1,32,10,16,8]
    float* out      = (float*)d_out;           // [128,10,16]
    digitcaps_routing<<<dim3(2, BB), 512, 0, stream>>>(x, Wm, out);
}